// Round 14
// baseline (652.514 us; speedup 1.0000x reference)
//
#include <hip/hip_runtime.h>
#include <hip/hip_fp16.h>
#include <float.h>
#include <math.h>

#define NN 100000
#define NE 1600000
#define D 64
#define LEAK 0.2f

#define SCAN_CHUNK 2048
#define NOFF (NN + 1)
#define NBLK ((NOFF + SCAN_CHUNK - 1) / SCAN_CHUNK)  // 49

// quarter-bucket binning geometry (64 rows per bucket)
#define NQB 1563           // ceil(100000/64)
#define NQBP 2048          // padded so the 512x4 scan covers it exactly
#define QCAP 1280          // capacity (mean 1024, +8 sigma)
#define BCHUNK 4096        // edges per bin block
#define BINBLKS ((NE + BCHUNK - 1) / BCHUNK)   // 391
#define CONVBLKS (NN * D / 4 / 512)            // 3125 (exact)
#define ASTR 65             // acc row stride (floats): breaks bank alignment

typedef unsigned long long ull;

__device__ __forceinline__ unsigned ford(float f) {
    unsigned u = __float_as_uint(f);
    return (u & 0x80000000u) ? ~u : (u | 0x80000000u);
}
__device__ __forceinline__ float funord(unsigned o) {
    return __uint_as_float((o & 0x80000000u) ? (o & 0x7fffffffu) : ~o);
}
__device__ __forceinline__ unsigned short f2bf(float f) {   // RNE f32->bf16
    unsigned u = __float_as_uint(f);
    unsigned r = u + 0x7fffu + ((u >> 16) & 1u);
    return (unsigned short)(r >> 16);
}
__device__ __forceinline__ float bf2f(unsigned short b) {
    return __uint_as_float((unsigned)b << 16);
}

// ---------------- k_prep: fused conv (blocks 0..CONVBLKS) + quarter-bin ----
// bin pack: col[16:0] | row[33:17] | f16(val)[49:34]; quarter key = row>>6
__global__ __launch_bounds__(512) void k_prep(const float4* __restrict__ embf,
                                              ushort4* __restrict__ emb16o,
                                              const int* __restrict__ rows,
                                              const int* __restrict__ cols,
                                              const float* __restrict__ vals,
                                              int* __restrict__ gcnt,
                                              ull* __restrict__ bins) {
    __shared__ unsigned hist[NQBP];   // 8 KB
    __shared__ unsigned esc[NQBP];    // 8 KB
    __shared__ unsigned gbase[NQBP];  // 8 KB
    __shared__ unsigned wsum[8];
    __shared__ ull staged[BCHUNK];    // 32 KB
    int tid = threadIdx.x;

    if (blockIdx.x < CONVBLKS) {      // ---- conv branch (exact, no guard)
        int i = blockIdx.x * 512 + tid;
        float4 f = embf[i];
        ushort4 r;
        r.x = f2bf(f.x); r.y = f2bf(f.y); r.z = f2bf(f.z); r.w = f2bf(f.w);
        emb16o[i] = r;
        return;
    }
    // ---- bin branch
    long base = (long)(blockIdx.x - CONVBLKS) * BCHUNK;
    int total = (int)min((long)BCHUNK, (long)NE - base);
    int lane = tid & 63, wv = tid >> 6;

    for (int i = tid; i < NQBP; i += 512) hist[i] = 0;
    __syncthreads();

    ull pk[8]; unsigned short rb[8]; unsigned short rr[8]; bool okf[8];
    #pragma unroll
    for (int k = 0; k < 8; k++) {
        long e = base + tid + k * 512;
        bool ok = e < NE;
        okf[k] = ok;
        int r = 0, c = 0; float v = 0.0f;
        if (ok) { r = rows[e]; c = cols[e]; v = vals[e]; }
        unsigned b = (unsigned)r >> 6;                   // quarter key
        rb[k] = (unsigned short)b;
        rr[k] = ok ? (unsigned short)atomicAdd(&hist[b], 1u) : (unsigned short)0;
        pk[k] = (ull)(unsigned)c | ((ull)(unsigned)r << 17)
              | ((ull)__half_as_ushort(__float2half(v)) << 34);
    }
    __syncthreads();

    // hierarchical exclusive scan: 4 keys/thread x 512 = NQBP exactly
    unsigned h0 = hist[tid * 4 + 0], h1 = hist[tid * 4 + 1],
             h2 = hist[tid * 4 + 2], h3 = hist[tid * 4 + 3];
    unsigned tsum = h0 + h1 + h2 + h3;
    unsigned v = tsum;
    #pragma unroll
    for (int off = 1; off < 64; off <<= 1) {
        unsigned t = __shfl_up(v, off, 64);
        if (lane >= off) v += t;
    }
    if (lane == 63) wsum[wv] = v;
    __syncthreads();
    if (tid == 0) {
        unsigned a = 0;
        #pragma unroll
        for (int k = 0; k < 8; k++) { unsigned t = wsum[k]; wsum[k] = a; a += t; }
    }
    __syncthreads();
    unsigned tb = v - tsum + wsum[wv];
    esc[tid * 4 + 0] = tb;
    esc[tid * 4 + 1] = tb + h0;
    esc[tid * 4 + 2] = tb + h0 + h1;
    esc[tid * 4 + 3] = tb + h0 + h1 + h2;
    __syncthreads();
    for (int i = tid; i < NQB; i += 512)
        if (hist[i] > 0) gbase[i] = (unsigned)atomicAdd(&gcnt[i], (int)hist[i]);
    __syncthreads();

    #pragma unroll
    for (int k = 0; k < 8; k++)
        if (okf[k]) staged[esc[rb[k]] + rr[k]] = pk[k];
    __syncthreads();

    for (int i = tid; i < total; i += 512) {
        ull p = staged[i];
        unsigned key = (unsigned)(p >> 23) & 0x7FFu;     // row>>6
        unsigned off = gbase[key] + ((unsigned)i - esc[key]);
        if (off < QCAP) bins[(long)key * QCAP + off] = p;
    }
}

// ---------------- k_aggbin: sort-free LDS accumulation -------------------
// One 64-row quarter-bucket per 256-thread block. Edges read ONCE, linearly;
// 16 lanes/edge; each lane does one ushort4 gather + 4 ds_add_f32 into
// acc[row][dim] (stride-65 rows -> 2-way bank alias, free). No sort passes.
__global__ __launch_bounds__(256, 8) void k_aggbin(const int* __restrict__ gcnt,
                                                   const ull* __restrict__ bins,
                                                   const unsigned short* __restrict__ emb16,
                                                   const float* __restrict__ w,
                                                   float* __restrict__ agg,
                                                   float* __restrict__ s,
                                                   unsigned* __restrict__ omax8) {
    __shared__ float acc[64 * ASTR];       // 16.6 KB
    __shared__ float red[4];
    int qb = blockIdx.x;
    int tid = threadIdx.x, lane = tid & 63, wv = tid >> 6;
    int q = lane & 15, g = lane >> 4;
    int n = gcnt[qb]; if (n > QCAP) n = QCAP;

    for (int i = tid; i < 64 * ASTR; i += 256) acc[i] = 0.0f;
    __syncthreads();

    // wave wv owns edge range [e0,e1); 4 edges per step (one per 16-lane group)
    int chunk = (n + 3) >> 2;
    int e0 = wv * chunk, e1 = e0 + chunk; if (e1 > n) e1 = n;
    const ull* mybin = bins + (long)qb * QCAP;
    for (int base = e0; base < e1; base += 16) {
        #pragma unroll
        for (int j = 0; j < 4; ++j) {
            int e = base + j * 4 + g;
            if (e < e1) {
                ull p = mybin[e];                               // 16-lane broadcast
                unsigned rl = (unsigned)(p >> 17) & 63u;
                unsigned c  = (unsigned)p & 0x1FFFFu;
                float v = __half2float(__ushort_as_half((unsigned short)(p >> 34)));
                ushort4 u4 = *(const ushort4*)(emb16 + ((long)c << 6) + (q << 2));
                float* a = acc + rl * ASTR + (q << 2);
                atomicAdd(a + 0, v * bf2f(u4.x));
                atomicAdd(a + 1, v * bf2f(u4.y));
                atomicAdd(a + 2, v * bf2f(u4.z));
                atomicAdd(a + 3, v * bf2f(u4.w));
            }
        }
    }
    __syncthreads();

    // epilogue: 16 groups x 4 passes = 64 rows; write agg + fused score/max
    float4 wl = ((const float4*)w)[q];
    float wmax = -FLT_MAX;
    for (int pass = 0; pass < 4; ++pass) {
        int rl = wv * 16 + pass * 4 + g;
        int node = (qb << 6) + rl;
        const float* a = acc + rl * ASTR + (q << 2);
        float a0 = a[0], a1 = a[1], a2 = a[2], a3 = a[3];
        float t = a0 * wl.x + a1 * wl.y + a2 * wl.z + a3 * wl.w;
        #pragma unroll
        for (int off = 8; off; off >>= 1) t += __shfl_xor(t, off, 16);
        if (node < NN) {
            ((float4*)agg)[((long)node << 4) + q] = make_float4(a0, a1, a2, a3);
            if (q == 0) s[node] = t;
            wmax = fmaxf(wmax, t);
        }
    }
    #pragma unroll
    for (int off = 32; off; off >>= 1) wmax = fmaxf(wmax, __shfl_xor(wmax, off, 64));
    if (lane == 0) red[wv] = wmax;
    __syncthreads();
    if (tid == 0) {
        float mx = fmaxf(fmaxf(red[0], red[1]), fmaxf(red[2], red[3]));
        atomicMax(&omax8[blockIdx.x & 7], ford(mx));
    }
}

// ---------------- CSR build (tier C fallback) ----------------
__global__ __launch_bounds__(256) void k_hist(const int4* __restrict__ rows4,
                                              int* __restrict__ cnt) {
    int t = blockIdx.x * 256 + threadIdx.x;
    if (t >= NE / 4) return;
    int4 r = rows4[t];
    atomicAdd(&cnt[r.x], 1);
    atomicAdd(&cnt[r.y], 1);
    atomicAdd(&cnt[r.z], 1);
    atomicAdd(&cnt[r.w], 1);
}

__global__ __launch_bounds__(256) void k_scanA(const int* __restrict__ cnt,
                                               int* __restrict__ partial) {
    int base = blockIdx.x * SCAN_CHUNK + threadIdx.x * 8;
    int s = 0;
    #pragma unroll
    for (int k = 0; k < 8; k++) { int i = base + k; if (i < NOFF) s += cnt[i]; }
    __shared__ int red[256];
    red[threadIdx.x] = s;
    __syncthreads();
    for (int off = 128; off; off >>= 1) {
        if (threadIdx.x < off) red[threadIdx.x] += red[threadIdx.x + off];
        __syncthreads();
    }
    if (threadIdx.x == 0) partial[blockIdx.x] = red[0];
}

__global__ void k_scanB(int* __restrict__ partial) {
    int l = threadIdx.x;
    int v = (l < NBLK) ? partial[l] : 0;
    int orig = v;
    #pragma unroll
    for (int off = 1; off < 64; off <<= 1) {
        int t = __shfl_up(v, off, 64);
        if (l >= off) v += t;
    }
    if (l < NBLK) partial[l] = v - orig;
}

__global__ __launch_bounds__(256) void k_scanC(const int* __restrict__ cnt,
                                               const int* __restrict__ partial,
                                               int* __restrict__ offs,
                                               int* __restrict__ cursor) {
    __shared__ int sdata[256];
    int tid = threadIdx.x;
    int base = blockIdx.x * SCAN_CHUNK + tid * 8;
    int v[8]; int s = 0;
    #pragma unroll
    for (int k = 0; k < 8; k++) { int i = base + k; v[k] = (i < NOFF) ? cnt[i] : 0; s += v[k]; }
    sdata[tid] = s;
    __syncthreads();
    for (int off = 1; off < 256; off <<= 1) {
        int t = 0;
        if (tid >= off) t = sdata[tid - off];
        __syncthreads();
        sdata[tid] += t;
        __syncthreads();
    }
    int excl = sdata[tid] - s + partial[blockIdx.x];
    #pragma unroll
    for (int k = 0; k < 8; k++) {
        int i = base + k;
        if (i < NOFF) {
            offs[i] = excl;
            if (i < NN) cursor[i] = excl;
            excl += v[k];
        }
    }
}

__global__ __launch_bounds__(256) void k_scatcsr(const int* __restrict__ rows,
                                                 const int* __restrict__ cols,
                                                 const float* __restrict__ vals,
                                                 int* __restrict__ cursor,
                                                 ull* __restrict__ pairs) {
    int e = blockIdx.x * 256 + threadIdx.x;
    if (e >= NE) return;
    int pos = atomicAdd(&cursor[rows[e]], 1);
    pairs[pos] = (ull)(unsigned)cols[e] | ((ull)__float_as_uint(vals[e]) << 32);
}

__global__ __launch_bounds__(256) void k_agg32(const ull* __restrict__ pairs,
                                               const int* __restrict__ offs,
                                               const float* __restrict__ embeds,
                                               const float* __restrict__ w,
                                               float* __restrict__ agg,
                                               float* __restrict__ s) {
    int node = (blockIdx.x * 256 + threadIdx.x) >> 6;
    int lane = threadIdx.x & 63;
    if (node >= NN) return;
    int st = offs[node], en = offs[node + 1];
    float acc = 0.0f;
    for (int base = st; base < en; base += 64) {
        int nk = en - base; if (nk > 64) nk = 64;
        ull p = (base + lane < en) ? pairs[base + lane] : 0ull;
        unsigned clo = (unsigned)p;
        unsigned vhi = (unsigned)(p >> 32);
        #pragma unroll 8
        for (int j = 0; j < nk; ++j) {
            int c   = __shfl((int)clo, j, 64);
            float v = __uint_as_float((unsigned)__shfl((int)vhi, j, 64));
            acc = fmaf(v, embeds[(long)c * D + lane], acc);
        }
    }
    agg[(long)node * D + lane] = acc;
    float t = acc * w[lane];
    #pragma unroll
    for (int off = 32; off; off >>= 1) t += __shfl_down(t, off, 64);
    if (lane == 0) s[node] = t;
}

// ---------------- softmax reductions ----------------
__global__ __launch_bounds__(256) void k_smax(const float* __restrict__ s,
                                              unsigned* __restrict__ omax8) {
    __shared__ float red[4];
    int i = blockIdx.x * 256 + threadIdx.x;
    float m = (i < NN) ? s[i] : -FLT_MAX;
    #pragma unroll
    for (int off = 32; off; off >>= 1) m = fmaxf(m, __shfl_down(m, off, 64));
    int lane = threadIdx.x & 63, wv = threadIdx.x >> 6;
    if (lane == 0) red[wv] = m;
    __syncthreads();
    if (threadIdx.x == 0) {
        m = fmaxf(fmaxf(red[0], red[1]), fmaxf(red[2], red[3]));
        atomicMax(&omax8[blockIdx.x & 7], ford(m));
    }
}

__global__ __launch_bounds__(256) void k_ssum(const float* __restrict__ s,
                                              const unsigned* __restrict__ omax8,
                                              float* __restrict__ sums8) {
    __shared__ float red[4];
    float m = -FLT_MAX;
    #pragma unroll
    for (int k = 0; k < 8; k++) m = fmaxf(m, funord(omax8[k]));
    int i = blockIdx.x * 256 + threadIdx.x;
    float a = (i < NN) ? expf(s[i] - m) : 0.0f;
    #pragma unroll
    for (int off = 32; off; off >>= 1) a += __shfl_down(a, off, 64);
    int lane = threadIdx.x & 63, wv = threadIdx.x >> 6;
    if (lane == 0) red[wv] = a;
    __syncthreads();
    if (threadIdx.x == 0)
        atomicAdd(&sums8[blockIdx.x & 7], red[0] + red[1] + red[2] + red[3]);
}

__global__ __launch_bounds__(256) void k_out(float* __restrict__ agg,
                                             const float* __restrict__ s,
                                             const unsigned* __restrict__ omax8,
                                             const float* __restrict__ sums8) {
    int i = blockIdx.x * 256 + threadIdx.x;   // float4 index
    if (i >= NN * (D / 4)) return;
    int n = i >> 4;
    float m = -FLT_MAX, sum = 0.0f;
    #pragma unroll
    for (int k = 0; k < 8; k++) { m = fmaxf(m, funord(omax8[k])); sum += sums8[k]; }
    float sc = expf(s[n] - m) / sum;
    float4 x = ((float4*)agg)[i];
    x.x *= sc; x.y *= sc; x.z *= sc; x.w *= sc;
    x.x = x.x > 0.0f ? x.x : LEAK * x.x;
    x.y = x.y > 0.0f ? x.y : LEAK * x.y;
    x.z = x.z > 0.0f ? x.z : LEAK * x.z;
    x.w = x.w > 0.0f ? x.w : LEAK * x.w;
    ((float4*)agg)[i] = x;
}

// ---------------- tier D: atomic fallback ----------------
__global__ __launch_bounds__(256) void k_edge(const int* __restrict__ rows,
                                              const int* __restrict__ cols,
                                              const float* __restrict__ vals,
                                              const float* __restrict__ embeds,
                                              float* __restrict__ agg) {
    int t = blockIdx.x * 256 + threadIdx.x;
    int e = t >> 4;
    int q = t & 15;
    if (e >= NE) return;
    int r = rows[e];
    int c = cols[e];
    float v = vals[e];
    const float4 x = *(const float4*)(embeds + (long)c * D + q * 4);
    float* dst = agg + (long)r * D + q * 4;
    unsafeAtomicAdd(dst + 0, v * x.x);
    unsafeAtomicAdd(dst + 1, v * x.y);
    unsafeAtomicAdd(dst + 2, v * x.z);
    unsafeAtomicAdd(dst + 3, v * x.w);
}

__global__ __launch_bounds__(256) void k_score(const float* __restrict__ agg,
                                               const float* __restrict__ w,
                                               float* __restrict__ s) {
    int node = (blockIdx.x * 256 + threadIdx.x) >> 6;
    int lane = threadIdx.x & 63;
    if (node >= NN) return;
    float v = agg[(long)node * D + lane] * w[lane];
    #pragma unroll
    for (int off = 32; off; off >>= 1) v += __shfl_down(v, off, 64);
    if (lane == 0) s[node] = v;
}

extern "C" void kernel_launch(void* const* d_in, const int* in_sizes, int n_in,
                              void* d_out, int out_size, void* d_ws, size_t ws_size,
                              hipStream_t stream) {
    const int*   rows   = (const int*)d_in[0];
    const int*   cols   = (const int*)d_in[1];
    const float* vals   = (const float*)d_in[2];
    const float* embeds = (const float*)d_in[3];
    const float* w      = (const float*)d_in[4];
    float* out = (float*)d_out;                            // doubles as agg buffer

    char* wsb = (char*)d_ws;
    float*    s     = (float*)(wsb);                       // 0 .. 400KB
    unsigned* omax8 = (unsigned*)(wsb + 0x70000);          // 32B
    float*    sums8 = (float*)   (wsb + 0x70020);          // 32B
    int*      gcnt  = (int*)     (wsb + 0x70040);          // NQB ints

    // emb16 @1MB (12.8MB), bins @0xE00000 (1563*1280*8 = 16.0MB)
    const size_t needNew = 0xE00000ull + (size_t)NQB * QCAP * 8;    // ~30.7MB
    const size_t needC   = 0x200000ull + (size_t)NE * 8;            // ~14.9MB

    const int nb_nodes = NN * 64 / 256;
    const int nb_sc    = (NN + 255) / 256;
    const int nb_e     = (NE + 255) / 256;
    const int nb_e4    = (NE / 4 + 255) / 256;
    const int nb_v4    = NN * D / 4 / 256;

    // zero omax8 + sums8 + gcnt every call (all accumulated into)
    hipMemsetAsync(wsb + 0x70000, 0, 64 + NQB * sizeof(int), stream);

    if (ws_size >= needNew) {
        unsigned short* emb16 = (unsigned short*)(wsb + 0x100000);
        ull* bins = (ull*)(wsb + 0xE00000);
        k_prep  <<<CONVBLKS + BINBLKS, 512, 0, stream>>>((const float4*)embeds,
                 (ushort4*)emb16, rows, cols, vals, gcnt, bins);
        k_aggbin<<<NQB, 256, 0, stream>>>(gcnt, bins, emb16, w, out, s, omax8);
    } else if (ws_size >= needC) {
        int* offs    = (int*)(wsb + 0x80000);
        int* partial = (int*)(wsb + 0xF0000);
        int* cnt     = (int*)(wsb + 0x100000);
        int* cursor  = (int*)(wsb + 0x180000);
        ull* pairs   = (ull*)(wsb + 0x200000);
        hipMemsetAsync(cnt, 0, (size_t)NOFF * sizeof(int), stream);
        k_hist   <<<nb_e4, 256, 0, stream>>>((const int4*)rows, cnt);
        k_scanA  <<<NBLK, 256, 0, stream>>>(cnt, partial);
        k_scanB  <<<1, 64, 0, stream>>>(partial);
        k_scanC  <<<NBLK, 256, 0, stream>>>(cnt, partial, offs, cursor);
        k_scatcsr<<<nb_e, 256, 0, stream>>>(rows, cols, vals, cursor, pairs);
        k_agg32  <<<nb_nodes, 256, 0, stream>>>(pairs, offs, embeds, w, out, s);
        k_smax   <<<nb_sc, 256, 0, stream>>>(s, omax8);
    } else {
        hipMemsetAsync(out, 0, (size_t)NN * D * sizeof(float), stream);
        k_edge <<<NE * 16 / 256, 256, 0, stream>>>(rows, cols, vals, embeds, out);
        k_score<<<nb_nodes, 256, 0, stream>>>(out, w, s);
        k_smax <<<nb_sc, 256, 0, stream>>>(s, omax8);
    }

    k_ssum<<<nb_sc, 256, 0, stream>>>(s, omax8, sums8);
    k_out <<<nb_v4, 256, 0, stream>>>(out, s, omax8, sums8);
}

// Round 15
// 112.196 us; speedup vs baseline: 5.8159x; 5.8159x over previous
//
#include <hip/hip_runtime.h>
#include <hip/hip_fp16.h>
#include <float.h>
#include <math.h>

#define NN 100000
#define NE 1600000
#define D 64
#define LEAK 0.2f

#define SCAN_CHUNK 2048
#define NOFF (NN + 1)
#define NBLK ((NOFF + SCAN_CHUNK - 1) / SCAN_CHUNK)  // 49

// quarter-bucket binning geometry (64 rows per bucket)
#define NQB 1563           // ceil(100000/64)
#define NQBP 2048          // padded so the 512x4 scan covers it exactly
#define QCAP 1280          // capacity (mean 1024, +8 sigma)
#define BCHUNK 4096        // edges per bin block
#define BINBLKS ((NE + BCHUNK - 1) / BCHUNK)   // 391
#define CONVBLKS (NN * D / 4 / 512)            // 3125 (exact)

typedef unsigned long long ull;

__device__ __forceinline__ unsigned ford(float f) {
    unsigned u = __float_as_uint(f);
    return (u & 0x80000000u) ? ~u : (u | 0x80000000u);
}
__device__ __forceinline__ float funord(unsigned o) {
    return __uint_as_float((o & 0x80000000u) ? (o & 0x7fffffffu) : ~o);
}
__device__ __forceinline__ unsigned short f2bf(float f) {   // RNE f32->bf16
    unsigned u = __float_as_uint(f);
    unsigned r = u + 0x7fffu + ((u >> 16) & 1u);
    return (unsigned short)(r >> 16);
}
__device__ __forceinline__ float bf2f(unsigned short b) {
    return __uint_as_float((unsigned)b << 16);
}

// ---------------- k_prep: fused conv (blocks 0..CONVBLKS) + quarter-bin ----
// bin pack: col[16:0] | row[33:17] | f16(val)[49:34]; quarter key = row>>6
// hist[] is reused for global reservations after the scan (saves 8KB LDS).
__global__ __launch_bounds__(512) void k_prep(const float4* __restrict__ embf,
                                              ushort4* __restrict__ emb16o,
                                              const int* __restrict__ rows,
                                              const int* __restrict__ cols,
                                              const float* __restrict__ vals,
                                              int* __restrict__ gcnt,
                                              ull* __restrict__ bins) {
    __shared__ unsigned hist[NQBP];   // 8 KB (counts, then reservations)
    __shared__ unsigned esc[NQBP];    // 8 KB (block-local exclusive scan)
    __shared__ unsigned wsum[8];
    __shared__ ull staged[BCHUNK];    // 32 KB  -> 48KB total, 3 blocks/CU
    int tid = threadIdx.x;

    if (blockIdx.x < CONVBLKS) {      // ---- conv branch (exact, no guard)
        int i = blockIdx.x * 512 + tid;
        float4 f = embf[i];
        ushort4 r;
        r.x = f2bf(f.x); r.y = f2bf(f.y); r.z = f2bf(f.z); r.w = f2bf(f.w);
        emb16o[i] = r;
        return;
    }
    // ---- bin branch
    long base = (long)(blockIdx.x - CONVBLKS) * BCHUNK;
    int total = (int)min((long)BCHUNK, (long)NE - base);
    int lane = tid & 63, wv = tid >> 6;

    for (int i = tid; i < NQBP; i += 512) hist[i] = 0;
    __syncthreads();

    ull pk[8]; unsigned short rb[8]; unsigned short rr[8]; bool okf[8];
    #pragma unroll
    for (int k = 0; k < 8; k++) {
        long e = base + tid + k * 512;
        bool ok = e < NE;
        okf[k] = ok;
        int r = 0, c = 0; float v = 0.0f;
        if (ok) { r = rows[e]; c = cols[e]; v = vals[e]; }
        unsigned b = (unsigned)r >> 6;                   // quarter key
        rb[k] = (unsigned short)b;
        rr[k] = ok ? (unsigned short)atomicAdd(&hist[b], 1u) : (unsigned short)0;
        pk[k] = (ull)(unsigned)c | ((ull)(unsigned)r << 17)
              | ((ull)__half_as_ushort(__float2half(v)) << 34);
    }
    __syncthreads();

    // hierarchical exclusive scan: 4 keys/thread x 512 = NQBP exactly
    unsigned h0 = hist[tid * 4 + 0], h1 = hist[tid * 4 + 1],
             h2 = hist[tid * 4 + 2], h3 = hist[tid * 4 + 3];
    unsigned tsum = h0 + h1 + h2 + h3;
    unsigned v = tsum;
    #pragma unroll
    for (int off = 1; off < 64; off <<= 1) {
        unsigned t = __shfl_up(v, off, 64);
        if (lane >= off) v += t;
    }
    if (lane == 63) wsum[wv] = v;
    __syncthreads();
    if (tid == 0) {
        unsigned a = 0;
        #pragma unroll
        for (int k = 0; k < 8; k++) { unsigned t = wsum[k]; wsum[k] = a; a += t; }
    }
    __syncthreads();
    unsigned tb = v - tsum + wsum[wv];
    esc[tid * 4 + 0] = tb;
    esc[tid * 4 + 1] = tb + h0;
    esc[tid * 4 + 2] = tb + h0 + h1;
    esc[tid * 4 + 3] = tb + h0 + h1 + h2;
    __syncthreads();
    // reserve global space; overwrite hist[i] with the reservation base
    for (int i = tid; i < NQB; i += 512) {
        unsigned h = hist[i];
        if (h > 0) hist[i] = (unsigned)atomicAdd(&gcnt[i], (int)h);
    }
    __syncthreads();

    #pragma unroll
    for (int k = 0; k < 8; k++)
        if (okf[k]) staged[esc[rb[k]] + rr[k]] = pk[k];
    __syncthreads();

    for (int i = tid; i < total; i += 512) {
        ull p = staged[i];
        unsigned key = (unsigned)(p >> 23) & 0x7FFu;     // row>>6
        unsigned off = hist[key] + ((unsigned)i - esc[key]);
        if (off < QCAP) bins[(long)key * QCAP + off] = p;
    }
}

// ---------------- k_aggbin: register-staged sorted scatter + gather ------
// One 64-row quarter-bucket per 256-thread block. Bins read ONCE into
// registers; rank via native int LDS atomics; scatter from registers into
// row-sorted arr[]; 16-lane/row gather loop. NO float LDS atomics (CAS trap).
__global__ __launch_bounds__(256, 8) void k_aggbin(const int* __restrict__ gcnt,
                                                   const ull* __restrict__ bins,
                                                   const unsigned short* __restrict__ emb16,
                                                   const float* __restrict__ w,
                                                   float* __restrict__ agg,
                                                   float* __restrict__ s,
                                                   unsigned* __restrict__ omax8) {
    __shared__ ull arr[QCAP];              // 10 KB
    __shared__ unsigned cnt[64];
    __shared__ unsigned csc[64];
    __shared__ float red[4];
    int qb = blockIdx.x;
    int tid = threadIdx.x, lane = tid & 63, wv = tid >> 6;
    int n = gcnt[qb]; if (n > QCAP) n = QCAP;

    if (tid < 64) cnt[tid] = 0;
    __syncthreads();

    // single global read -> registers; rank via int LDS atomic
    ull pk[5]; unsigned char rl[5]; unsigned short rr[5]; bool okf[5];
    #pragma unroll
    for (int k = 0; k < 5; k++) {
        int e = tid + k * 256;
        bool ok = e < n;
        okf[k] = ok;
        ull p = ok ? bins[(long)qb * QCAP + e] : 0ull;
        pk[k] = p;
        unsigned r = (unsigned)(p >> 17) & 63u;
        rl[k] = (unsigned char)r;
        rr[k] = ok ? (unsigned short)atomicAdd(&cnt[r], 1u) : (unsigned short)0;
    }
    __syncthreads();

    // exclusive scan of 64 counters in wave 0
    if (tid < 64) {
        unsigned h = cnt[tid], vv = h;
        #pragma unroll
        for (int off = 1; off < 64; off <<= 1) {
            unsigned t = __shfl_up(vv, off, 64);
            if (lane >= off) vv += t;
        }
        csc[tid] = vv - h;
    }
    __syncthreads();

    // scatter from registers into sorted LDS position
    #pragma unroll
    for (int k = 0; k < 5; k++)
        if (okf[k]) {
            unsigned pos = csc[rl[k]] + rr[k];
            if (pos < QCAP) arr[pos] = pk[k];
        }
    __syncthreads();

    // aggregate: 4 waves x 4 passes x 4 rows = 64 rows; 16 lanes per row
    int q = lane & 15, g = lane >> 4;
    float4 wl = ((const float4*)w)[q];
    float wmax = -FLT_MAX;
    for (int pass = 0; pass < 4; ++pass) {
        int rlidx = wv * 16 + pass * 4 + g;
        int node = (qb << 6) + rlidx;
        int base0 = (int)csc[rlidx];
        int cn = (node < NN) ? (int)cnt[rlidx] : 0;
        if (base0 + cn > QCAP) cn = (base0 < QCAP) ? (QCAP - base0) : 0;
        float a0 = 0.f, a1 = 0.f, a2 = 0.f, a3 = 0.f;
        for (int c4 = 0; ; ++c4) {
            if (__all((c4 << 4) >= cn)) break;
            #pragma unroll
            for (int jj = 0; jj < 16; ++jj) {
                int j = (c4 << 4) + jj;
                if (j < cn) {
                    ull p = arr[base0 + j];
                    unsigned c = (unsigned)p & 0x1FFFFu;
                    float v = __half2float(__ushort_as_half((unsigned short)(p >> 34)));
                    ushort4 u4 = *(const ushort4*)(emb16 + ((long)c << 6) + (q << 2));
                    a0 = fmaf(v, bf2f(u4.x), a0);
                    a1 = fmaf(v, bf2f(u4.y), a1);
                    a2 = fmaf(v, bf2f(u4.z), a2);
                    a3 = fmaf(v, bf2f(u4.w), a3);
                }
            }
        }
        float t = a0 * wl.x + a1 * wl.y + a2 * wl.z + a3 * wl.w;
        #pragma unroll
        for (int off = 8; off; off >>= 1) t += __shfl_xor(t, off, 16);
        if (node < NN) {
            ((float4*)agg)[((long)node << 4) + q] = make_float4(a0, a1, a2, a3);
            if (q == 0) s[node] = t;
            wmax = fmaxf(wmax, t);
        }
    }
    #pragma unroll
    for (int off = 32; off; off >>= 1) wmax = fmaxf(wmax, __shfl_xor(wmax, off, 64));
    if (lane == 0) red[wv] = wmax;
    __syncthreads();
    if (tid == 0) {
        float mx = fmaxf(fmaxf(red[0], red[1]), fmaxf(red[2], red[3]));
        atomicMax(&omax8[blockIdx.x & 7], ford(mx));
    }
}

// ---------------- CSR build (tier C fallback) ----------------
__global__ __launch_bounds__(256) void k_hist(const int4* __restrict__ rows4,
                                              int* __restrict__ cnt) {
    int t = blockIdx.x * 256 + threadIdx.x;
    if (t >= NE / 4) return;
    int4 r = rows4[t];
    atomicAdd(&cnt[r.x], 1);
    atomicAdd(&cnt[r.y], 1);
    atomicAdd(&cnt[r.z], 1);
    atomicAdd(&cnt[r.w], 1);
}

__global__ __launch_bounds__(256) void k_scanA(const int* __restrict__ cnt,
                                               int* __restrict__ partial) {
    int base = blockIdx.x * SCAN_CHUNK + threadIdx.x * 8;
    int s = 0;
    #pragma unroll
    for (int k = 0; k < 8; k++) { int i = base + k; if (i < NOFF) s += cnt[i]; }
    __shared__ int red[256];
    red[threadIdx.x] = s;
    __syncthreads();
    for (int off = 128; off; off >>= 1) {
        if (threadIdx.x < off) red[threadIdx.x] += red[threadIdx.x + off];
        __syncthreads();
    }
    if (threadIdx.x == 0) partial[blockIdx.x] = red[0];
}

__global__ void k_scanB(int* __restrict__ partial) {
    int l = threadIdx.x;
    int v = (l < NBLK) ? partial[l] : 0;
    int orig = v;
    #pragma unroll
    for (int off = 1; off < 64; off <<= 1) {
        int t = __shfl_up(v, off, 64);
        if (l >= off) v += t;
    }
    if (l < NBLK) partial[l] = v - orig;
}

__global__ __launch_bounds__(256) void k_scanC(const int* __restrict__ cnt,
                                               const int* __restrict__ partial,
                                               int* __restrict__ offs,
                                               int* __restrict__ cursor) {
    __shared__ int sdata[256];
    int tid = threadIdx.x;
    int base = blockIdx.x * SCAN_CHUNK + tid * 8;
    int v[8]; int s = 0;
    #pragma unroll
    for (int k = 0; k < 8; k++) { int i = base + k; v[k] = (i < NOFF) ? cnt[i] : 0; s += v[k]; }
    sdata[tid] = s;
    __syncthreads();
    for (int off = 1; off < 256; off <<= 1) {
        int t = 0;
        if (tid >= off) t = sdata[tid - off];
        __syncthreads();
        sdata[tid] += t;
        __syncthreads();
    }
    int excl = sdata[tid] - s + partial[blockIdx.x];
    #pragma unroll
    for (int k = 0; k < 8; k++) {
        int i = base + k;
        if (i < NOFF) {
            offs[i] = excl;
            if (i < NN) cursor[i] = excl;
            excl += v[k];
        }
    }
}

__global__ __launch_bounds__(256) void k_scatcsr(const int* __restrict__ rows,
                                                 const int* __restrict__ cols,
                                                 const float* __restrict__ vals,
                                                 int* __restrict__ cursor,
                                                 ull* __restrict__ pairs) {
    int e = blockIdx.x * 256 + threadIdx.x;
    if (e >= NE) return;
    int pos = atomicAdd(&cursor[rows[e]], 1);
    pairs[pos] = (ull)(unsigned)cols[e] | ((ull)__float_as_uint(vals[e]) << 32);
}

__global__ __launch_bounds__(256) void k_agg32(const ull* __restrict__ pairs,
                                               const int* __restrict__ offs,
                                               const float* __restrict__ embeds,
                                               const float* __restrict__ w,
                                               float* __restrict__ agg,
                                               float* __restrict__ s) {
    int node = (blockIdx.x * 256 + threadIdx.x) >> 6;
    int lane = threadIdx.x & 63;
    if (node >= NN) return;
    int st = offs[node], en = offs[node + 1];
    float acc = 0.0f;
    for (int base = st; base < en; base += 64) {
        int nk = en - base; if (nk > 64) nk = 64;
        ull p = (base + lane < en) ? pairs[base + lane] : 0ull;
        unsigned clo = (unsigned)p;
        unsigned vhi = (unsigned)(p >> 32);
        #pragma unroll 8
        for (int j = 0; j < nk; ++j) {
            int c   = __shfl((int)clo, j, 64);
            float v = __uint_as_float((unsigned)__shfl((int)vhi, j, 64));
            acc = fmaf(v, embeds[(long)c * D + lane], acc);
        }
    }
    agg[(long)node * D + lane] = acc;
    float t = acc * w[lane];
    #pragma unroll
    for (int off = 32; off; off >>= 1) t += __shfl_down(t, off, 64);
    if (lane == 0) s[node] = t;
}

// ---------------- softmax reductions ----------------
__global__ __launch_bounds__(256) void k_smax(const float* __restrict__ s,
                                              unsigned* __restrict__ omax8) {
    __shared__ float red[4];
    int i = blockIdx.x * 256 + threadIdx.x;
    float m = (i < NN) ? s[i] : -FLT_MAX;
    #pragma unroll
    for (int off = 32; off; off >>= 1) m = fmaxf(m, __shfl_down(m, off, 64));
    int lane = threadIdx.x & 63, wv = threadIdx.x >> 6;
    if (lane == 0) red[wv] = m;
    __syncthreads();
    if (threadIdx.x == 0) {
        m = fmaxf(fmaxf(red[0], red[1]), fmaxf(red[2], red[3]));
        atomicMax(&omax8[blockIdx.x & 7], ford(m));
    }
}

__global__ __launch_bounds__(256) void k_ssum(const float* __restrict__ s,
                                              const unsigned* __restrict__ omax8,
                                              float* __restrict__ sums8) {
    __shared__ float red[4];
    float m = -FLT_MAX;
    #pragma unroll
    for (int k = 0; k < 8; k++) m = fmaxf(m, funord(omax8[k]));
    int i = blockIdx.x * 256 + threadIdx.x;
    float a = (i < NN) ? expf(s[i] - m) : 0.0f;
    #pragma unroll
    for (int off = 32; off; off >>= 1) a += __shfl_down(a, off, 64);
    int lane = threadIdx.x & 63, wv = threadIdx.x >> 6;
    if (lane == 0) red[wv] = a;
    __syncthreads();
    if (threadIdx.x == 0)
        atomicAdd(&sums8[blockIdx.x & 7], red[0] + red[1] + red[2] + red[3]);
}

__global__ __launch_bounds__(256) void k_out(float* __restrict__ agg,
                                             const float* __restrict__ s,
                                             const unsigned* __restrict__ omax8,
                                             const float* __restrict__ sums8) {
    int i = blockIdx.x * 256 + threadIdx.x;   // float4 index
    if (i >= NN * (D / 4)) return;
    int n = i >> 4;
    float m = -FLT_MAX, sum = 0.0f;
    #pragma unroll
    for (int k = 0; k < 8; k++) { m = fmaxf(m, funord(omax8[k])); sum += sums8[k]; }
    float sc = expf(s[n] - m) / sum;
    float4 x = ((float4*)agg)[i];
    x.x *= sc; x.y *= sc; x.z *= sc; x.w *= sc;
    x.x = x.x > 0.0f ? x.x : LEAK * x.x;
    x.y = x.y > 0.0f ? x.y : LEAK * x.y;
    x.z = x.z > 0.0f ? x.z : LEAK * x.z;
    x.w = x.w > 0.0f ? x.w : LEAK * x.w;
    ((float4*)agg)[i] = x;
}

// ---------------- tier D: atomic fallback ----------------
__global__ __launch_bounds__(256) void k_edge(const int* __restrict__ rows,
                                              const int* __restrict__ cols,
                                              const float* __restrict__ vals,
                                              const float* __restrict__ embeds,
                                              float* __restrict__ agg) {
    int t = blockIdx.x * 256 + threadIdx.x;
    int e = t >> 4;
    int q = t & 15;
    if (e >= NE) return;
    int r = rows[e];
    int c = cols[e];
    float v = vals[e];
    const float4 x = *(const float4*)(embeds + (long)c * D + q * 4);
    float* dst = agg + (long)r * D + q * 4;
    unsafeAtomicAdd(dst + 0, v * x.x);
    unsafeAtomicAdd(dst + 1, v * x.y);
    unsafeAtomicAdd(dst + 2, v * x.z);
    unsafeAtomicAdd(dst + 3, v * x.w);
}

__global__ __launch_bounds__(256) void k_score(const float* __restrict__ agg,
                                               const float* __restrict__ w,
                                               float* __restrict__ s) {
    int node = (blockIdx.x * 256 + threadIdx.x) >> 6;
    int lane = threadIdx.x & 63;
    if (node >= NN) return;
    float v = agg[(long)node * D + lane] * w[lane];
    #pragma unroll
    for (int off = 32; off; off >>= 1) v += __shfl_down(v, off, 64);
    if (lane == 0) s[node] = v;
}

extern "C" void kernel_launch(void* const* d_in, const int* in_sizes, int n_in,
                              void* d_out, int out_size, void* d_ws, size_t ws_size,
                              hipStream_t stream) {
    const int*   rows   = (const int*)d_in[0];
    const int*   cols   = (const int*)d_in[1];
    const float* vals   = (const float*)d_in[2];
    const float* embeds = (const float*)d_in[3];
    const float* w      = (const float*)d_in[4];
    float* out = (float*)d_out;                            // doubles as agg buffer

    char* wsb = (char*)d_ws;
    float*    s     = (float*)(wsb);                       // 0 .. 400KB
    unsigned* omax8 = (unsigned*)(wsb + 0x70000);          // 32B
    float*    sums8 = (float*)   (wsb + 0x70020);          // 32B
    int*      gcnt  = (int*)     (wsb + 0x70040);          // NQB ints

    // emb16 @1MB (12.8MB), bins @0xE00000 (1563*1280*8 = 16.0MB)
    const size_t needNew = 0xE00000ull + (size_t)NQB * QCAP * 8;    // ~30.7MB
    const size_t needC   = 0x200000ull + (size_t)NE * 8;            // ~14.9MB

    const int nb_nodes = NN * 64 / 256;
    const int nb_sc    = (NN + 255) / 256;
    const int nb_e     = (NE + 255) / 256;
    const int nb_e4    = (NE / 4 + 255) / 256;
    const int nb_v4    = NN * D / 4 / 256;

    // zero omax8 + sums8 + gcnt every call (all accumulated into)
    hipMemsetAsync(wsb + 0x70000, 0, 64 + NQB * sizeof(int), stream);

    if (ws_size >= needNew) {
        unsigned short* emb16 = (unsigned short*)(wsb + 0x100000);
        ull* bins = (ull*)(wsb + 0xE00000);
        k_prep  <<<CONVBLKS + BINBLKS, 512, 0, stream>>>((const float4*)embeds,
                 (ushort4*)emb16, rows, cols, vals, gcnt, bins);
        k_aggbin<<<NQB, 256, 0, stream>>>(gcnt, bins, emb16, w, out, s, omax8);
    } else if (ws_size >= needC) {
        int* offs    = (int*)(wsb + 0x80000);
        int* partial = (int*)(wsb + 0xF0000);
        int* cnt     = (int*)(wsb + 0x100000);
        int* cursor  = (int*)(wsb + 0x180000);
        ull* pairs   = (ull*)(wsb + 0x200000);
        hipMemsetAsync(cnt, 0, (size_t)NOFF * sizeof(int), stream);
        k_hist   <<<nb_e4, 256, 0, stream>>>((const int4*)rows, cnt);
        k_scanA  <<<NBLK, 256, 0, stream>>>(cnt, partial);
        k_scanB  <<<1, 64, 0, stream>>>(partial);
        k_scanC  <<<NBLK, 256, 0, stream>>>(cnt, partial, offs, cursor);
        k_scatcsr<<<nb_e, 256, 0, stream>>>(rows, cols, vals, cursor, pairs);
        k_agg32  <<<nb_nodes, 256, 0, stream>>>(pairs, offs, embeds, w, out, s);
        k_smax   <<<nb_sc, 256, 0, stream>>>(s, omax8);
    } else {
        hipMemsetAsync(out, 0, (size_t)NN * D * sizeof(float), stream);
        k_edge <<<NE * 16 / 256, 256, 0, stream>>>(rows, cols, vals, embeds, out);
        k_score<<<nb_nodes, 256, 0, stream>>>(out, w, s);
        k_smax <<<nb_sc, 256, 0, stream>>>(s, omax8);
    }

    k_ssum<<<nb_sc, 256, 0, stream>>>(s, omax8, sums8);
    k_out <<<nb_v4, 256, 0, stream>>>(out, s, omax8, sums8);
}

// Round 16
// 110.324 us; speedup vs baseline: 5.9145x; 1.0170x over previous
//
#include <hip/hip_runtime.h>
#include <hip/hip_fp16.h>
#include <float.h>
#include <math.h>

#define NN 100000
#define NE 1600000
#define D 64
#define LEAK 0.2f

#define SCAN_CHUNK 2048
#define NOFF (NN + 1)
#define NBLK ((NOFF + SCAN_CHUNK - 1) / SCAN_CHUNK)  // 49

// quarter-bucket binning geometry (64 rows per bucket)
#define NQB 1563           // ceil(100000/64)
#define NQBP 2048          // padded so the 512x4 scan covers it exactly
#define QCAP 1280          // capacity (mean 1024, +8 sigma)
#define BCHUNK 4096        // edges per bin block
#define BINBLKS ((NE + BCHUNK - 1) / BCHUNK)   // 391
#define CONVBLKS (NN * D / 4 / 512)            // 3125 (exact)

typedef unsigned long long ull;

__device__ __forceinline__ unsigned ford(float f) {
    unsigned u = __float_as_uint(f);
    return (u & 0x80000000u) ? ~u : (u | 0x80000000u);
}
__device__ __forceinline__ float funord(unsigned o) {
    return __uint_as_float((o & 0x80000000u) ? (o & 0x7fffffffu) : ~o);
}
__device__ __forceinline__ unsigned short f2bf(float f) {   // RNE f32->bf16
    unsigned u = __float_as_uint(f);
    unsigned r = u + 0x7fffu + ((u >> 16) & 1u);
    return (unsigned short)(r >> 16);
}
__device__ __forceinline__ float bf2f(unsigned short b) {
    return __uint_as_float((unsigned)b << 16);
}

// ---------------- k_prep: fused conv (blocks 0..CONVBLKS) + quarter-bin ----
// bin pack: col[16:0] | row[33:17] | f16(val)[49:34]; quarter key = row>>6
// hist[] is reused for global reservations after the scan.
__global__ __launch_bounds__(512) void k_prep(const float4* __restrict__ embf,
                                              ushort4* __restrict__ emb16o,
                                              const int* __restrict__ rows,
                                              const int* __restrict__ cols,
                                              const float* __restrict__ vals,
                                              int* __restrict__ gcnt,
                                              ull* __restrict__ bins) {
    __shared__ unsigned hist[NQBP];   // 8 KB (counts, then reservations)
    __shared__ unsigned esc[NQBP];    // 8 KB (block-local exclusive scan)
    __shared__ unsigned wsum[8];
    __shared__ ull staged[BCHUNK];    // 32 KB  -> 48KB total, 3 blocks/CU
    int tid = threadIdx.x;

    if (blockIdx.x < CONVBLKS) {      // ---- conv branch (exact, no guard)
        int i = blockIdx.x * 512 + tid;
        float4 f = embf[i];
        ushort4 r;
        r.x = f2bf(f.x); r.y = f2bf(f.y); r.z = f2bf(f.z); r.w = f2bf(f.w);
        emb16o[i] = r;
        return;
    }
    // ---- bin branch
    long base = (long)(blockIdx.x - CONVBLKS) * BCHUNK;
    int total = (int)min((long)BCHUNK, (long)NE - base);
    int lane = tid & 63, wv = tid >> 6;

    for (int i = tid; i < NQBP; i += 512) hist[i] = 0;
    __syncthreads();

    ull pk[8]; unsigned short rb[8]; unsigned short rr[8]; bool okf[8];
    #pragma unroll
    for (int k = 0; k < 8; k++) {
        long e = base + tid + k * 512;
        bool ok = e < NE;
        okf[k] = ok;
        int r = 0, c = 0; float v = 0.0f;
        if (ok) { r = rows[e]; c = cols[e]; v = vals[e]; }
        unsigned b = (unsigned)r >> 6;                   // quarter key
        rb[k] = (unsigned short)b;
        rr[k] = ok ? (unsigned short)atomicAdd(&hist[b], 1u) : (unsigned short)0;
        pk[k] = (ull)(unsigned)c | ((ull)(unsigned)r << 17)
              | ((ull)__half_as_ushort(__float2half(v)) << 34);
    }
    __syncthreads();

    // hierarchical exclusive scan: 4 keys/thread x 512 = NQBP exactly
    unsigned h0 = hist[tid * 4 + 0], h1 = hist[tid * 4 + 1],
             h2 = hist[tid * 4 + 2], h3 = hist[tid * 4 + 3];
    unsigned tsum = h0 + h1 + h2 + h3;
    unsigned v = tsum;
    #pragma unroll
    for (int off = 1; off < 64; off <<= 1) {
        unsigned t = __shfl_up(v, off, 64);
        if (lane >= off) v += t;
    }
    if (lane == 63) wsum[wv] = v;
    __syncthreads();
    if (tid == 0) {
        unsigned a = 0;
        #pragma unroll
        for (int k = 0; k < 8; k++) { unsigned t = wsum[k]; wsum[k] = a; a += t; }
    }
    __syncthreads();
    unsigned tb = v - tsum + wsum[wv];
    esc[tid * 4 + 0] = tb;
    esc[tid * 4 + 1] = tb + h0;
    esc[tid * 4 + 2] = tb + h0 + h1;
    esc[tid * 4 + 3] = tb + h0 + h1 + h2;
    __syncthreads();
    // reserve global space; overwrite hist[i] with the reservation base
    for (int i = tid; i < NQB; i += 512) {
        unsigned h = hist[i];
        if (h > 0) hist[i] = (unsigned)atomicAdd(&gcnt[i], (int)h);
    }
    __syncthreads();

    #pragma unroll
    for (int k = 0; k < 8; k++)
        if (okf[k]) staged[esc[rb[k]] + rr[k]] = pk[k];
    __syncthreads();

    for (int i = tid; i < total; i += 512) {
        ull p = staged[i];
        unsigned key = (unsigned)(p >> 23) & 0x7FFu;     // row>>6
        unsigned off = hist[key] + ((unsigned)i - esc[key]);
        if (off < QCAP) bins[(long)key * QCAP + off] = p;
    }
}

// ---------------- k_aggbin: 512-thread (8-wave) per quarter-bucket -------
// One 64-row bucket per block; register-staged single global read; native
// int LDS atomics rank; row-sorted arr[]; 16-lane/row gather, 2 rows/group.
// LDS ~10.8KB, waves-limited: 4 blocks/CU = 32 waves/CU (max occupancy).
__global__ __launch_bounds__(512) void k_aggbin(const int* __restrict__ gcnt,
                                                const ull* __restrict__ bins,
                                                const unsigned short* __restrict__ emb16,
                                                const float* __restrict__ w,
                                                float* __restrict__ agg,
                                                float* __restrict__ s,
                                                unsigned* __restrict__ omax8) {
    __shared__ ull arr[QCAP];              // 10 KB
    __shared__ unsigned cnt[64];
    __shared__ unsigned csc[64];
    __shared__ float red[8];
    int qb = blockIdx.x;
    int tid = threadIdx.x, lane = tid & 63, wv = tid >> 6;
    int n = gcnt[qb]; if (n > QCAP) n = QCAP;

    if (tid < 64) cnt[tid] = 0;
    __syncthreads();

    // single global read -> registers; rank via native int LDS atomic
    ull pk[3]; unsigned char rl[3]; unsigned short rr[3]; bool okf[3];
    #pragma unroll
    for (int k = 0; k < 3; k++) {
        int e = tid + k * 512;
        bool ok = e < n;
        okf[k] = ok;
        ull p = ok ? bins[(long)qb * QCAP + e] : 0ull;
        pk[k] = p;
        unsigned r = (unsigned)(p >> 17) & 63u;
        rl[k] = (unsigned char)r;
        rr[k] = ok ? (unsigned short)atomicAdd(&cnt[r], 1u) : (unsigned short)0;
    }
    __syncthreads();

    // exclusive scan of 64 counters in wave 0
    if (tid < 64) {
        unsigned h = cnt[tid], vv = h;
        #pragma unroll
        for (int off = 1; off < 64; off <<= 1) {
            unsigned t = __shfl_up(vv, off, 64);
            if (lane >= off) vv += t;
        }
        csc[tid] = vv - h;
    }
    __syncthreads();

    // scatter from registers into sorted LDS position
    #pragma unroll
    for (int k = 0; k < 3; k++)
        if (okf[k]) {
            unsigned pos = csc[rl[k]] + rr[k];
            if (pos < QCAP) arr[pos] = pk[k];
        }
    __syncthreads();

    // aggregate: 8 waves x 4 groups x 2 passes = 64 rows; 16 lanes per row
    int q = lane & 15, g = lane >> 4;
    float4 wl = ((const float4*)w)[q];
    float wmax = -FLT_MAX;
    for (int pass = 0; pass < 2; ++pass) {
        int rlidx = pass * 32 + wv * 4 + g;
        int node = (qb << 6) + rlidx;
        int base0 = (int)csc[rlidx];
        int cn = (node < NN) ? (int)cnt[rlidx] : 0;
        if (base0 + cn > QCAP) cn = (base0 < QCAP) ? (QCAP - base0) : 0;
        float a0 = 0.f, a1 = 0.f, a2 = 0.f, a3 = 0.f;
        for (int c4 = 0; ; ++c4) {
            if (__all((c4 << 4) >= cn)) break;
            #pragma unroll
            for (int jj = 0; jj < 16; ++jj) {
                int j = (c4 << 4) + jj;
                if (j < cn) {
                    ull p = arr[base0 + j];
                    unsigned c = (unsigned)p & 0x1FFFFu;
                    float v = __half2float(__ushort_as_half((unsigned short)(p >> 34)));
                    ushort4 u4 = *(const ushort4*)(emb16 + ((long)c << 6) + (q << 2));
                    a0 = fmaf(v, bf2f(u4.x), a0);
                    a1 = fmaf(v, bf2f(u4.y), a1);
                    a2 = fmaf(v, bf2f(u4.z), a2);
                    a3 = fmaf(v, bf2f(u4.w), a3);
                }
            }
        }
        float t = a0 * wl.x + a1 * wl.y + a2 * wl.z + a3 * wl.w;
        #pragma unroll
        for (int off = 8; off; off >>= 1) t += __shfl_xor(t, off, 16);
        if (node < NN) {
            ((float4*)agg)[((long)node << 4) + q] = make_float4(a0, a1, a2, a3);
            if (q == 0) s[node] = t;
            wmax = fmaxf(wmax, t);
        }
    }
    #pragma unroll
    for (int off = 32; off; off >>= 1) wmax = fmaxf(wmax, __shfl_xor(wmax, off, 64));
    if (lane == 0) red[wv] = wmax;
    __syncthreads();
    if (tid == 0) {
        float mx = red[0];
        #pragma unroll
        for (int k = 1; k < 8; ++k) mx = fmaxf(mx, red[k]);
        atomicMax(&omax8[blockIdx.x & 7], ford(mx));
    }
}

// ---------------- CSR build (tier C fallback) ----------------
__global__ __launch_bounds__(256) void k_hist(const int4* __restrict__ rows4,
                                              int* __restrict__ cnt) {
    int t = blockIdx.x * 256 + threadIdx.x;
    if (t >= NE / 4) return;
    int4 r = rows4[t];
    atomicAdd(&cnt[r.x], 1);
    atomicAdd(&cnt[r.y], 1);
    atomicAdd(&cnt[r.z], 1);
    atomicAdd(&cnt[r.w], 1);
}

__global__ __launch_bounds__(256) void k_scanA(const int* __restrict__ cnt,
                                               int* __restrict__ partial) {
    int base = blockIdx.x * SCAN_CHUNK + threadIdx.x * 8;
    int s = 0;
    #pragma unroll
    for (int k = 0; k < 8; k++) { int i = base + k; if (i < NOFF) s += cnt[i]; }
    __shared__ int red[256];
    red[threadIdx.x] = s;
    __syncthreads();
    for (int off = 128; off; off >>= 1) {
        if (threadIdx.x < off) red[threadIdx.x] += red[threadIdx.x + off];
        __syncthreads();
    }
    if (threadIdx.x == 0) partial[blockIdx.x] = red[0];
}

__global__ void k_scanB(int* __restrict__ partial) {
    int l = threadIdx.x;
    int v = (l < NBLK) ? partial[l] : 0;
    int orig = v;
    #pragma unroll
    for (int off = 1; off < 64; off <<= 1) {
        int t = __shfl_up(v, off, 64);
        if (l >= off) v += t;
    }
    if (l < NBLK) partial[l] = v - orig;
}

__global__ __launch_bounds__(256) void k_scanC(const int* __restrict__ cnt,
                                               const int* __restrict__ partial,
                                               int* __restrict__ offs,
                                               int* __restrict__ cursor) {
    __shared__ int sdata[256];
    int tid = threadIdx.x;
    int base = blockIdx.x * SCAN_CHUNK + tid * 8;
    int v[8]; int s = 0;
    #pragma unroll
    for (int k = 0; k < 8; k++) { int i = base + k; v[k] = (i < NOFF) ? cnt[i] : 0; s += v[k]; }
    sdata[tid] = s;
    __syncthreads();
    for (int off = 1; off < 256; off <<= 1) {
        int t = 0;
        if (tid >= off) t = sdata[tid - off];
        __syncthreads();
        sdata[tid] += t;
        __syncthreads();
    }
    int excl = sdata[tid] - s + partial[blockIdx.x];
    #pragma unroll
    for (int k = 0; k < 8; k++) {
        int i = base + k;
        if (i < NOFF) {
            offs[i] = excl;
            if (i < NN) cursor[i] = excl;
            excl += v[k];
        }
    }
}

__global__ __launch_bounds__(256) void k_scatcsr(const int* __restrict__ rows,
                                                 const int* __restrict__ cols,
                                                 const float* __restrict__ vals,
                                                 int* __restrict__ cursor,
                                                 ull* __restrict__ pairs) {
    int e = blockIdx.x * 256 + threadIdx.x;
    if (e >= NE) return;
    int pos = atomicAdd(&cursor[rows[e]], 1);
    pairs[pos] = (ull)(unsigned)cols[e] | ((ull)__float_as_uint(vals[e]) << 32);
}

__global__ __launch_bounds__(256) void k_agg32(const ull* __restrict__ pairs,
                                               const int* __restrict__ offs,
                                               const float* __restrict__ embeds,
                                               const float* __restrict__ w,
                                               float* __restrict__ agg,
                                               float* __restrict__ s) {
    int node = (blockIdx.x * 256 + threadIdx.x) >> 6;
    int lane = threadIdx.x & 63;
    if (node >= NN) return;
    int st = offs[node], en = offs[node + 1];
    float acc = 0.0f;
    for (int base = st; base < en; base += 64) {
        int nk = en - base; if (nk > 64) nk = 64;
        ull p = (base + lane < en) ? pairs[base + lane] : 0ull;
        unsigned clo = (unsigned)p;
        unsigned vhi = (unsigned)(p >> 32);
        #pragma unroll 8
        for (int j = 0; j < nk; ++j) {
            int c   = __shfl((int)clo, j, 64);
            float v = __uint_as_float((unsigned)__shfl((int)vhi, j, 64));
            acc = fmaf(v, embeds[(long)c * D + lane], acc);
        }
    }
    agg[(long)node * D + lane] = acc;
    float t = acc * w[lane];
    #pragma unroll
    for (int off = 32; off; off >>= 1) t += __shfl_down(t, off, 64);
    if (lane == 0) s[node] = t;
}

// ---------------- softmax reductions ----------------
__global__ __launch_bounds__(256) void k_smax(const float* __restrict__ s,
                                              unsigned* __restrict__ omax8) {
    __shared__ float red[4];
    int i = blockIdx.x * 256 + threadIdx.x;
    float m = (i < NN) ? s[i] : -FLT_MAX;
    #pragma unroll
    for (int off = 32; off; off >>= 1) m = fmaxf(m, __shfl_down(m, off, 64));
    int lane = threadIdx.x & 63, wv = threadIdx.x >> 6;
    if (lane == 0) red[wv] = m;
    __syncthreads();
    if (threadIdx.x == 0) {
        m = fmaxf(fmaxf(red[0], red[1]), fmaxf(red[2], red[3]));
        atomicMax(&omax8[blockIdx.x & 7], ford(m));
    }
}

__global__ __launch_bounds__(256) void k_ssum(const float* __restrict__ s,
                                              const unsigned* __restrict__ omax8,
                                              float* __restrict__ sums8) {
    __shared__ float red[4];
    float m = -FLT_MAX;
    #pragma unroll
    for (int k = 0; k < 8; k++) m = fmaxf(m, funord(omax8[k]));
    int i = blockIdx.x * 256 + threadIdx.x;
    float a = (i < NN) ? expf(s[i] - m) : 0.0f;
    #pragma unroll
    for (int off = 32; off; off >>= 1) a += __shfl_down(a, off, 64);
    int lane = threadIdx.x & 63, wv = threadIdx.x >> 6;
    if (lane == 0) red[wv] = a;
    __syncthreads();
    if (threadIdx.x == 0)
        atomicAdd(&sums8[blockIdx.x & 7], red[0] + red[1] + red[2] + red[3]);
}

__global__ __launch_bounds__(256) void k_out(float* __restrict__ agg,
                                             const float* __restrict__ s,
                                             const unsigned* __restrict__ omax8,
                                             const float* __restrict__ sums8) {
    int i = blockIdx.x * 256 + threadIdx.x;   // float4 index
    if (i >= NN * (D / 4)) return;
    int n = i >> 4;
    float m = -FLT_MAX, sum = 0.0f;
    #pragma unroll
    for (int k = 0; k < 8; k++) { m = fmaxf(m, funord(omax8[k])); sum += sums8[k]; }
    float sc = expf(s[n] - m) / sum;
    float4 x = ((float4*)agg)[i];
    x.x *= sc; x.y *= sc; x.z *= sc; x.w *= sc;
    x.x = x.x > 0.0f ? x.x : LEAK * x.x;
    x.y = x.y > 0.0f ? x.y : LEAK * x.y;
    x.z = x.z > 0.0f ? x.z : LEAK * x.z;
    x.w = x.w > 0.0f ? x.w : LEAK * x.w;
    ((float4*)agg)[i] = x;
}

// ---------------- tier D: atomic fallback ----------------
__global__ __launch_bounds__(256) void k_edge(const int* __restrict__ rows,
                                              const int* __restrict__ cols,
                                              const float* __restrict__ vals,
                                              const float* __restrict__ embeds,
                                              float* __restrict__ agg) {
    int t = blockIdx.x * 256 + threadIdx.x;
    int e = t >> 4;
    int q = t & 15;
    if (e >= NE) return;
    int r = rows[e];
    int c = cols[e];
    float v = vals[e];
    const float4 x = *(const float4*)(embeds + (long)c * D + q * 4);
    float* dst = agg + (long)r * D + q * 4;
    unsafeAtomicAdd(dst + 0, v * x.x);
    unsafeAtomicAdd(dst + 1, v * x.y);
    unsafeAtomicAdd(dst + 2, v * x.z);
    unsafeAtomicAdd(dst + 3, v * x.w);
}

__global__ __launch_bounds__(256) void k_score(const float* __restrict__ agg,
                                               const float* __restrict__ w,
                                               float* __restrict__ s) {
    int node = (blockIdx.x * 256 + threadIdx.x) >> 6;
    int lane = threadIdx.x & 63;
    if (node >= NN) return;
    float v = agg[(long)node * D + lane] * w[lane];
    #pragma unroll
    for (int off = 32; off; off >>= 1) v += __shfl_down(v, off, 64);
    if (lane == 0) s[node] = v;
}

extern "C" void kernel_launch(void* const* d_in, const int* in_sizes, int n_in,
                              void* d_out, int out_size, void* d_ws, size_t ws_size,
                              hipStream_t stream) {
    const int*   rows   = (const int*)d_in[0];
    const int*   cols   = (const int*)d_in[1];
    const float* vals   = (const float*)d_in[2];
    const float* embeds = (const float*)d_in[3];
    const float* w      = (const float*)d_in[4];
    float* out = (float*)d_out;                            // doubles as agg buffer

    char* wsb = (char*)d_ws;
    float*    s     = (float*)(wsb);                       // 0 .. 400KB
    unsigned* omax8 = (unsigned*)(wsb + 0x70000);          // 32B
    float*    sums8 = (float*)   (wsb + 0x70020);          // 32B
    int*      gcnt  = (int*)     (wsb + 0x70040);          // NQB ints

    // emb16 @1MB (12.8MB), bins @0xE00000 (1563*1280*8 = 16.0MB)
    const size_t needNew = 0xE00000ull + (size_t)NQB * QCAP * 8;    // ~30.7MB
    const size_t needC   = 0x200000ull + (size_t)NE * 8;            // ~14.9MB

    const int nb_nodes = NN * 64 / 256;
    const int nb_sc    = (NN + 255) / 256;
    const int nb_e     = (NE + 255) / 256;
    const int nb_e4    = (NE / 4 + 255) / 256;
    const int nb_v4    = NN * D / 4 / 256;

    // zero omax8 + sums8 + gcnt every call (all accumulated into)
    hipMemsetAsync(wsb + 0x70000, 0, 64 + NQB * sizeof(int), stream);

    if (ws_size >= needNew) {
        unsigned short* emb16 = (unsigned short*)(wsb + 0x100000);
        ull* bins = (ull*)(wsb + 0xE00000);
        k_prep  <<<CONVBLKS + BINBLKS, 512, 0, stream>>>((const float4*)embeds,
                 (ushort4*)emb16, rows, cols, vals, gcnt, bins);
        k_aggbin<<<NQB, 512, 0, stream>>>(gcnt, bins, emb16, w, out, s, omax8);
    } else if (ws_size >= needC) {
        int* offs    = (int*)(wsb + 0x80000);
        int* partial = (int*)(wsb + 0xF0000);
        int* cnt     = (int*)(wsb + 0x100000);
        int* cursor  = (int*)(wsb + 0x180000);
        ull* pairs   = (ull*)(wsb + 0x200000);
        hipMemsetAsync(cnt, 0, (size_t)NOFF * sizeof(int), stream);
        k_hist   <<<nb_e4, 256, 0, stream>>>((const int4*)rows, cnt);
        k_scanA  <<<NBLK, 256, 0, stream>>>(cnt, partial);
        k_scanB  <<<1, 64, 0, stream>>>(partial);
        k_scanC  <<<NBLK, 256, 0, stream>>>(cnt, partial, offs, cursor);
        k_scatcsr<<<nb_e, 256, 0, stream>>>(rows, cols, vals, cursor, pairs);
        k_agg32  <<<nb_nodes, 256, 0, stream>>>(pairs, offs, embeds, w, out, s);
        k_smax   <<<nb_sc, 256, 0, stream>>>(s, omax8);
    } else {
        hipMemsetAsync(out, 0, (size_t)NN * D * sizeof(float), stream);
        k_edge <<<NE * 16 / 256, 256, 0, stream>>>(rows, cols, vals, embeds, out);
        k_score<<<nb_nodes, 256, 0, stream>>>(out, w, s);
        k_smax <<<nb_sc, 256, 0, stream>>>(s, omax8);
    }

    k_ssum<<<nb_sc, 256, 0, stream>>>(s, omax8, sums8);
    k_out <<<nb_v4, 256, 0, stream>>>(out, s, omax8, sums8);
}

// Round 17
// 109.591 us; speedup vs baseline: 5.9541x; 1.0067x over previous
//
#include <hip/hip_runtime.h>
#include <hip/hip_fp16.h>
#include <float.h>
#include <math.h>

#define NN 100000
#define NE 1600000
#define D 64
#define LEAK 0.2f

#define SCAN_CHUNK 2048
#define NOFF (NN + 1)
#define NBLK ((NOFF + SCAN_CHUNK - 1) / SCAN_CHUNK)  // 49

// quarter-bucket binning geometry (64 rows per bucket)
#define NQB 1563           // ceil(100000/64)
#define NQBP 2048          // padded so the 512x4 scan covers it exactly
#define QCAP 1280          // capacity (mean 1024, +8 sigma)
#define BCHUNK 4096        // edges per bin block
#define BINBLKS ((NE + BCHUNK - 1) / BCHUNK)   // 391
#define CONVBLKS (NN * D / 4 / 512)            // 3125 (exact)
#define AGGBLKS 1024       // persistent blocks (4/CU x 256 CU)

typedef unsigned long long ull;

__device__ __forceinline__ unsigned ford(float f) {
    unsigned u = __float_as_uint(f);
    return (u & 0x80000000u) ? ~u : (u | 0x80000000u);
}
__device__ __forceinline__ float funord(unsigned o) {
    return __uint_as_float((o & 0x80000000u) ? (o & 0x7fffffffu) : ~o);
}
__device__ __forceinline__ unsigned short f2bf(float f) {   // RNE f32->bf16
    unsigned u = __float_as_uint(f);
    unsigned r = u + 0x7fffu + ((u >> 16) & 1u);
    return (unsigned short)(r >> 16);
}
__device__ __forceinline__ float bflo(unsigned u) {         // low bf16 of u32
    return __uint_as_float(u << 16);
}
__device__ __forceinline__ float bfhi(unsigned u) {         // high bf16 of u32
    return __uint_as_float(u & 0xffff0000u);
}

// ---------------- k_prep: fused conv (blocks 0..CONVBLKS) + quarter-bin ----
// bin pack: col[16:0] | row[33:17] | f16(val)[49:34]; quarter key = row>>6
__global__ __launch_bounds__(512) void k_prep(const float4* __restrict__ embf,
                                              ushort4* __restrict__ emb16o,
                                              const int* __restrict__ rows,
                                              const int* __restrict__ cols,
                                              const float* __restrict__ vals,
                                              int* __restrict__ gcnt,
                                              ull* __restrict__ bins) {
    __shared__ unsigned hist[NQBP];   // 8 KB (counts, then reservations)
    __shared__ unsigned esc[NQBP];    // 8 KB (block-local exclusive scan)
    __shared__ unsigned wsum[8];
    __shared__ ull staged[BCHUNK];    // 32 KB
    int tid = threadIdx.x;

    if (blockIdx.x < CONVBLKS) {      // ---- conv branch (exact, no guard)
        int i = blockIdx.x * 512 + tid;
        float4 f = embf[i];
        ushort4 r;
        r.x = f2bf(f.x); r.y = f2bf(f.y); r.z = f2bf(f.z); r.w = f2bf(f.w);
        emb16o[i] = r;
        return;
    }
    // ---- bin branch
    long base = (long)(blockIdx.x - CONVBLKS) * BCHUNK;
    int total = (int)min((long)BCHUNK, (long)NE - base);
    int lane = tid & 63, wv = tid >> 6;

    for (int i = tid; i < NQBP; i += 512) hist[i] = 0;
    __syncthreads();

    ull pk[8]; unsigned short rb[8]; unsigned short rr[8]; bool okf[8];
    #pragma unroll
    for (int k = 0; k < 8; k++) {
        long e = base + tid + k * 512;
        bool ok = e < NE;
        okf[k] = ok;
        int r = 0, c = 0; float v = 0.0f;
        if (ok) { r = rows[e]; c = cols[e]; v = vals[e]; }
        unsigned b = (unsigned)r >> 6;                   // quarter key
        rb[k] = (unsigned short)b;
        rr[k] = ok ? (unsigned short)atomicAdd(&hist[b], 1u) : (unsigned short)0;
        pk[k] = (ull)(unsigned)c | ((ull)(unsigned)r << 17)
              | ((ull)__half_as_ushort(__float2half(v)) << 34);
    }
    __syncthreads();

    // hierarchical exclusive scan: 4 keys/thread x 512 = NQBP exactly
    unsigned h0 = hist[tid * 4 + 0], h1 = hist[tid * 4 + 1],
             h2 = hist[tid * 4 + 2], h3 = hist[tid * 4 + 3];
    unsigned tsum = h0 + h1 + h2 + h3;
    unsigned v = tsum;
    #pragma unroll
    for (int off = 1; off < 64; off <<= 1) {
        unsigned t = __shfl_up(v, off, 64);
        if (lane >= off) v += t;
    }
    if (lane == 63) wsum[wv] = v;
    __syncthreads();
    if (tid == 0) {
        unsigned a = 0;
        #pragma unroll
        for (int k = 0; k < 8; k++) { unsigned t = wsum[k]; wsum[k] = a; a += t; }
    }
    __syncthreads();
    unsigned tb = v - tsum + wsum[wv];
    esc[tid * 4 + 0] = tb;
    esc[tid * 4 + 1] = tb + h0;
    esc[tid * 4 + 2] = tb + h0 + h1;
    esc[tid * 4 + 3] = tb + h0 + h1 + h2;
    __syncthreads();
    // reserve global space; overwrite hist[i] with the reservation base
    for (int i = tid; i < NQB; i += 512) {
        unsigned h = hist[i];
        if (h > 0) hist[i] = (unsigned)atomicAdd(&gcnt[i], (int)h);
    }
    __syncthreads();

    #pragma unroll
    for (int k = 0; k < 8; k++)
        if (okf[k]) staged[esc[rb[k]] + rr[k]] = pk[k];
    __syncthreads();

    for (int i = tid; i < total; i += 512) {
        ull p = staged[i];
        unsigned key = (unsigned)(p >> 23) & 0x7FFu;     // row>>6
        unsigned off = hist[key] + ((unsigned)i - esc[key]);
        if (off < QCAP) bins[(long)key * QCAP + off] = p;
    }
}

// ---------------- k_aggbin: persistent work-stealing, 8-lane/edge gather --
// 1024 persistent 512-thread blocks grab buckets via global ticket (no tail).
// Per bucket: register-staged read + int-atomic rank sort into arr[];
// gather: 8 lanes per edge (uint4 = 8 dims each), 8 edges in flight/wave,
// each 8-lane group owns exactly ONE row (64 groups = 64 rows).
__global__ __launch_bounds__(512) void k_aggbin(const int* __restrict__ gcnt,
                                                const ull* __restrict__ bins,
                                                const unsigned short* __restrict__ emb16,
                                                const float* __restrict__ w,
                                                float* __restrict__ agg,
                                                float* __restrict__ s,
                                                unsigned* __restrict__ omax8,
                                                int* __restrict__ ticket) {
    __shared__ ull arr[QCAP];              // 10 KB
    __shared__ unsigned cnt[64];
    __shared__ unsigned csc[64];
    __shared__ float red[8];
    __shared__ int sqb;
    int tid = threadIdx.x, lane = tid & 63, wv = tid >> 6;
    int q = tid & 7, gi = tid >> 3;        // 64 groups of 8 lanes; group = row

    float4 wl0 = ((const float4*)w)[q * 2];
    float4 wl1 = ((const float4*)w)[q * 2 + 1];

    for (;;) {
        __syncthreads();                   // LDS from prior bucket fully consumed
        if (tid == 0) sqb = atomicAdd(ticket, 1);
        if (tid < 64) cnt[tid] = 0;
        __syncthreads();
        int qb = sqb;
        if (qb >= NQB) return;
        int n = gcnt[qb]; if (n > QCAP) n = QCAP;

        // single global read -> registers; rank via native int LDS atomic
        ull pk[3]; unsigned char rl[3]; unsigned short rr[3]; bool okf[3];
        #pragma unroll
        for (int k = 0; k < 3; k++) {
            int e = tid + k * 512;
            bool ok = e < n;
            okf[k] = ok;
            ull p = ok ? bins[(long)qb * QCAP + e] : 0ull;
            pk[k] = p;
            unsigned r = (unsigned)(p >> 17) & 63u;
            rl[k] = (unsigned char)r;
            rr[k] = ok ? (unsigned short)atomicAdd(&cnt[r], 1u) : (unsigned short)0;
        }
        __syncthreads();

        // exclusive scan of 64 counters in wave 0
        if (tid < 64) {
            unsigned h = cnt[tid], vv = h;
            #pragma unroll
            for (int off = 1; off < 64; off <<= 1) {
                unsigned t = __shfl_up(vv, off, 64);
                if (lane >= off) vv += t;
            }
            csc[tid] = vv - h;
        }
        __syncthreads();

        // scatter from registers into sorted LDS position
        #pragma unroll
        for (int k = 0; k < 3; k++)
            if (okf[k]) {
                unsigned pos = csc[rl[k]] + rr[k];
                if (pos < QCAP) arr[pos] = pk[k];
            }
        __syncthreads();

        // gather: group gi owns row gi; 8 lanes x 8 dims each
        int node = (qb << 6) + gi;
        int base0 = (int)csc[gi];
        int cn = (node < NN) ? (int)cnt[gi] : 0;
        if (base0 + cn > QCAP) cn = (base0 < QCAP) ? (QCAP - base0) : 0;
        float a0 = 0.f, a1 = 0.f, a2 = 0.f, a3 = 0.f;
        float a4 = 0.f, a5 = 0.f, a6 = 0.f, a7 = 0.f;
        for (int c16 = 0; ; ++c16) {
            if (__all((c16 << 4) >= cn)) break;
            #pragma unroll
            for (int jj = 0; jj < 16; ++jj) {
                int j = (c16 << 4) + jj;
                if (j < cn) {
                    ull p = arr[base0 + j];                 // 8-lane broadcast
                    unsigned c = (unsigned)p & 0x1FFFFu;
                    float v = __half2float(__ushort_as_half((unsigned short)(p >> 34)));
                    uint4 u = *(const uint4*)(emb16 + ((long)c << 6) + (q << 3));
                    a0 = fmaf(v, bflo(u.x), a0);
                    a1 = fmaf(v, bfhi(u.x), a1);
                    a2 = fmaf(v, bflo(u.y), a2);
                    a3 = fmaf(v, bfhi(u.y), a3);
                    a4 = fmaf(v, bflo(u.z), a4);
                    a5 = fmaf(v, bfhi(u.z), a5);
                    a6 = fmaf(v, bflo(u.w), a6);
                    a7 = fmaf(v, bfhi(u.w), a7);
                }
            }
        }
        float t = a0 * wl0.x + a1 * wl0.y + a2 * wl0.z + a3 * wl0.w
                + a4 * wl1.x + a5 * wl1.y + a6 * wl1.z + a7 * wl1.w;
        #pragma unroll
        for (int off = 4; off; off >>= 1) t += __shfl_xor(t, off, 8);
        float wmax = -FLT_MAX;
        if (node < NN) {
            long b4 = ((long)node << 4) + (q << 1);
            ((float4*)agg)[b4]     = make_float4(a0, a1, a2, a3);
            ((float4*)agg)[b4 + 1] = make_float4(a4, a5, a6, a7);
            if (q == 0) s[node] = t;
            wmax = t;
        }
        #pragma unroll
        for (int off = 32; off; off >>= 1) wmax = fmaxf(wmax, __shfl_xor(wmax, off, 64));
        if (lane == 0) red[wv] = wmax;
        __syncthreads();
        if (tid == 0) {
            float mx = red[0];
            #pragma unroll
            for (int k = 1; k < 8; ++k) mx = fmaxf(mx, red[k]);
            atomicMax(&omax8[qb & 7], ford(mx));
        }
    }
}

// ---------------- CSR build (tier C fallback) ----------------
__global__ __launch_bounds__(256) void k_hist(const int4* __restrict__ rows4,
                                              int* __restrict__ cnt) {
    int t = blockIdx.x * 256 + threadIdx.x;
    if (t >= NE / 4) return;
    int4 r = rows4[t];
    atomicAdd(&cnt[r.x], 1);
    atomicAdd(&cnt[r.y], 1);
    atomicAdd(&cnt[r.z], 1);
    atomicAdd(&cnt[r.w], 1);
}

__global__ __launch_bounds__(256) void k_scanA(const int* __restrict__ cnt,
                                               int* __restrict__ partial) {
    int base = blockIdx.x * SCAN_CHUNK + threadIdx.x * 8;
    int s = 0;
    #pragma unroll
    for (int k = 0; k < 8; k++) { int i = base + k; if (i < NOFF) s += cnt[i]; }
    __shared__ int red[256];
    red[threadIdx.x] = s;
    __syncthreads();
    for (int off = 128; off; off >>= 1) {
        if (threadIdx.x < off) red[threadIdx.x] += red[threadIdx.x + off];
        __syncthreads();
    }
    if (threadIdx.x == 0) partial[blockIdx.x] = red[0];
}

__global__ void k_scanB(int* __restrict__ partial) {
    int l = threadIdx.x;
    int v = (l < NBLK) ? partial[l] : 0;
    int orig = v;
    #pragma unroll
    for (int off = 1; off < 64; off <<= 1) {
        int t = __shfl_up(v, off, 64);
        if (l >= off) v += t;
    }
    if (l < NBLK) partial[l] = v - orig;
}

__global__ __launch_bounds__(256) void k_scanC(const int* __restrict__ cnt,
                                               const int* __restrict__ partial,
                                               int* __restrict__ offs,
                                               int* __restrict__ cursor) {
    __shared__ int sdata[256];
    int tid = threadIdx.x;
    int base = blockIdx.x * SCAN_CHUNK + tid * 8;
    int v[8]; int s = 0;
    #pragma unroll
    for (int k = 0; k < 8; k++) { int i = base + k; v[k] = (i < NOFF) ? cnt[i] : 0; s += v[k]; }
    sdata[tid] = s;
    __syncthreads();
    for (int off = 1; off < 256; off <<= 1) {
        int t = 0;
        if (tid >= off) t = sdata[tid - off];
        __syncthreads();
        sdata[tid] += t;
        __syncthreads();
    }
    int excl = sdata[tid] - s + partial[blockIdx.x];
    #pragma unroll
    for (int k = 0; k < 8; k++) {
        int i = base + k;
        if (i < NOFF) {
            offs[i] = excl;
            if (i < NN) cursor[i] = excl;
            excl += v[k];
        }
    }
}

__global__ __launch_bounds__(256) void k_scatcsr(const int* __restrict__ rows,
                                                 const int* __restrict__ cols,
                                                 const float* __restrict__ vals,
                                                 int* __restrict__ cursor,
                                                 ull* __restrict__ pairs) {
    int e = blockIdx.x * 256 + threadIdx.x;
    if (e >= NE) return;
    int pos = atomicAdd(&cursor[rows[e]], 1);
    pairs[pos] = (ull)(unsigned)cols[e] | ((ull)__float_as_uint(vals[e]) << 32);
}

__global__ __launch_bounds__(256) void k_agg32(const ull* __restrict__ pairs,
                                               const int* __restrict__ offs,
                                               const float* __restrict__ embeds,
                                               const float* __restrict__ w,
                                               float* __restrict__ agg,
                                               float* __restrict__ s) {
    int node = (blockIdx.x * 256 + threadIdx.x) >> 6;
    int lane = threadIdx.x & 63;
    if (node >= NN) return;
    int st = offs[node], en = offs[node + 1];
    float acc = 0.0f;
    for (int base = st; base < en; base += 64) {
        int nk = en - base; if (nk > 64) nk = 64;
        ull p = (base + lane < en) ? pairs[base + lane] : 0ull;
        unsigned clo = (unsigned)p;
        unsigned vhi = (unsigned)(p >> 32);
        #pragma unroll 8
        for (int j = 0; j < nk; ++j) {
            int c   = __shfl((int)clo, j, 64);
            float v = __uint_as_float((unsigned)__shfl((int)vhi, j, 64));
            acc = fmaf(v, embeds[(long)c * D + lane], acc);
        }
    }
    agg[(long)node * D + lane] = acc;
    float t = acc * w[lane];
    #pragma unroll
    for (int off = 32; off; off >>= 1) t += __shfl_down(t, off, 64);
    if (lane == 0) s[node] = t;
}

// ---------------- softmax reductions ----------------
__global__ __launch_bounds__(256) void k_smax(const float* __restrict__ s,
                                              unsigned* __restrict__ omax8) {
    __shared__ float red[4];
    int i = blockIdx.x * 256 + threadIdx.x;
    float m = (i < NN) ? s[i] : -FLT_MAX;
    #pragma unroll
    for (int off = 32; off; off >>= 1) m = fmaxf(m, __shfl_down(m, off, 64));
    int lane = threadIdx.x & 63, wv = threadIdx.x >> 6;
    if (lane == 0) red[wv] = m;
    __syncthreads();
    if (threadIdx.x == 0) {
        m = fmaxf(fmaxf(red[0], red[1]), fmaxf(red[2], red[3]));
        atomicMax(&omax8[blockIdx.x & 7], ford(m));
    }
}

__global__ __launch_bounds__(256) void k_ssum(const float* __restrict__ s,
                                              const unsigned* __restrict__ omax8,
                                              float* __restrict__ sums8) {
    __shared__ float red[4];
    float m = -FLT_MAX;
    #pragma unroll
    for (int k = 0; k < 8; k++) m = fmaxf(m, funord(omax8[k]));
    int i = blockIdx.x * 256 + threadIdx.x;
    float a = (i < NN) ? expf(s[i] - m) : 0.0f;
    #pragma unroll
    for (int off = 32; off; off >>= 1) a += __shfl_down(a, off, 64);
    int lane = threadIdx.x & 63, wv = threadIdx.x >> 6;
    if (lane == 0) red[wv] = a;
    __syncthreads();
    if (threadIdx.x == 0)
        atomicAdd(&sums8[blockIdx.x & 7], red[0] + red[1] + red[2] + red[3]);
}

__global__ __launch_bounds__(256) void k_out(float* __restrict__ agg,
                                             const float* __restrict__ s,
                                             const unsigned* __restrict__ omax8,
                                             const float* __restrict__ sums8) {
    int i = blockIdx.x * 256 + threadIdx.x;   // float4 index
    if (i >= NN * (D / 4)) return;
    int n = i >> 4;
    float m = -FLT_MAX, sum = 0.0f;
    #pragma unroll
    for (int k = 0; k < 8; k++) { m = fmaxf(m, funord(omax8[k])); sum += sums8[k]; }
    float sc = expf(s[n] - m) / sum;
    float4 x = ((float4*)agg)[i];
    x.x *= sc; x.y *= sc; x.z *= sc; x.w *= sc;
    x.x = x.x > 0.0f ? x.x : LEAK * x.x;
    x.y = x.y > 0.0f ? x.y : LEAK * x.y;
    x.z = x.z > 0.0f ? x.z : LEAK * x.z;
    x.w = x.w > 0.0f ? x.w : LEAK * x.w;
    ((float4*)agg)[i] = x;
}

// ---------------- tier D: atomic fallback ----------------
__global__ __launch_bounds__(256) void k_edge(const int* __restrict__ rows,
                                              const int* __restrict__ cols,
                                              const float* __restrict__ vals,
                                              const float* __restrict__ embeds,
                                              float* __restrict__ agg) {
    int t = blockIdx.x * 256 + threadIdx.x;
    int e = t >> 4;
    int q = t & 15;
    if (e >= NE) return;
    int r = rows[e];
    int c = cols[e];
    float v = vals[e];
    const float4 x = *(const float4*)(embeds + (long)c * D + q * 4);
    float* dst = agg + (long)r * D + q * 4;
    unsafeAtomicAdd(dst + 0, v * x.x);
    unsafeAtomicAdd(dst + 1, v * x.y);
    unsafeAtomicAdd(dst + 2, v * x.z);
    unsafeAtomicAdd(dst + 3, v * x.w);
}

__global__ __launch_bounds__(256) void k_score(const float* __restrict__ agg,
                                               const float* __restrict__ w,
                                               float* __restrict__ s) {
    int node = (blockIdx.x * 256 + threadIdx.x) >> 6;
    int lane = threadIdx.x & 63;
    if (node >= NN) return;
    float v = agg[(long)node * D + lane] * w[lane];
    #pragma unroll
    for (int off = 32; off; off >>= 1) v += __shfl_down(v, off, 64);
    if (lane == 0) s[node] = v;
}

extern "C" void kernel_launch(void* const* d_in, const int* in_sizes, int n_in,
                              void* d_out, int out_size, void* d_ws, size_t ws_size,
                              hipStream_t stream) {
    const int*   rows   = (const int*)d_in[0];
    const int*   cols   = (const int*)d_in[1];
    const float* vals   = (const float*)d_in[2];
    const float* embeds = (const float*)d_in[3];
    const float* w      = (const float*)d_in[4];
    float* out = (float*)d_out;                            // doubles as agg buffer

    char* wsb = (char*)d_ws;
    float*    s      = (float*)(wsb);                      // 0 .. 400KB
    unsigned* omax8  = (unsigned*)(wsb + 0x70000);         // 32B
    float*    sums8  = (float*)   (wsb + 0x70020);         // 32B
    int*      gcnt   = (int*)     (wsb + 0x70040);         // NQB ints
    int*      ticket = (int*)     (wsb + 0x71F00);         // 4B (work-stealing)

    // emb16 @1MB (12.8MB), bins @0xE00000 (1563*1280*8 = 16.0MB)
    const size_t needNew = 0xE00000ull + (size_t)NQB * QCAP * 8;    // ~30.7MB
    const size_t needC   = 0x200000ull + (size_t)NE * 8;            // ~14.9MB

    const int nb_nodes = NN * 64 / 256;
    const int nb_sc    = (NN + 255) / 256;
    const int nb_e     = (NE + 255) / 256;
    const int nb_e4    = (NE / 4 + 255) / 256;
    const int nb_v4    = NN * D / 4 / 256;

    // zero omax8/sums8/gcnt/ticket every call (all accumulated into)
    hipMemsetAsync(wsb + 0x70000, 0, 0x2000, stream);

    if (ws_size >= needNew) {
        unsigned short* emb16 = (unsigned short*)(wsb + 0x100000);
        ull* bins = (ull*)(wsb + 0xE00000);
        k_prep  <<<CONVBLKS + BINBLKS, 512, 0, stream>>>((const float4*)embeds,
                 (ushort4*)emb16, rows, cols, vals, gcnt, bins);
        k_aggbin<<<AGGBLKS, 512, 0, stream>>>(gcnt, bins, emb16, w, out, s, omax8, ticket);
    } else if (ws_size >= needC) {
        int* offs    = (int*)(wsb + 0x80000);
        int* partial = (int*)(wsb + 0xF0000);
        int* cnt     = (int*)(wsb + 0x100000);
        int* cursor  = (int*)(wsb + 0x180000);
        ull* pairs   = (ull*)(wsb + 0x200000);
        hipMemsetAsync(cnt, 0, (size_t)NOFF * sizeof(int), stream);
        k_hist   <<<nb_e4, 256, 0, stream>>>((const int4*)rows, cnt);
        k_scanA  <<<NBLK, 256, 0, stream>>>(cnt, partial);
        k_scanB  <<<1, 64, 0, stream>>>(partial);
        k_scanC  <<<NBLK, 256, 0, stream>>>(cnt, partial, offs, cursor);
        k_scatcsr<<<nb_e, 256, 0, stream>>>(rows, cols, vals, cursor, pairs);
        k_agg32  <<<nb_nodes, 256, 0, stream>>>(pairs, offs, embeds, w, out, s);
        k_smax   <<<nb_sc, 256, 0, stream>>>(s, omax8);
    } else {
        hipMemsetAsync(out, 0, (size_t)NN * D * sizeof(float), stream);
        k_edge <<<NE * 16 / 256, 256, 0, stream>>>(rows, cols, vals, embeds, out);
        k_score<<<nb_nodes, 256, 0, stream>>>(out, w, s);
        k_smax <<<nb_sc, 256, 0, stream>>>(s, omax8);
    }

    k_ssum<<<nb_sc, 256, 0, stream>>>(s, omax8, sums8);
    k_out <<<nb_v4, 256, 0, stream>>>(out, s, omax8, sums8);
}